// Round 2
// baseline (945.291 us; speedup 1.0000x reference)
//
#include <hip/hip_runtime.h>
#include <math.h>

// GraphSwinWindowContext: B=32, H=W=192, C=64, WS=6, SS=3, NH=NW=32.
// Output has only B*32*32*4 = 131072 distinct C-vectors (constant per
// (window, quadrant) 3x3 patch) -> the two per-pixel 64x64 linears collapse
// from M=1.18M to M=131K rows.
//
// Round-2 change: runtime dtype dispatch. token_g (d_in[3]) is all-ones;
// first 32-bit word is 0x3F800000 for fp32, 0x3F803F80 for packed bf16.
// k_detect writes a flag; each kernel is templated <F32> and early-exits
// if not the live dtype. NaN in round 1 implicated fp32 inputs read as bf16.
//
// ws layout:
//   [0, 33554432)        : S fp32 [B][64][64][C]  (reused as ctx fp32 after k_token)
//   [33554432, 50331648) : tok fp32 [2][B][32][32][C]
//   [50331648, +4)       : dtype flag (1 = fp32, 0 = bf16)

#define HH 192
#define WW 192
#define CC 64

__device__ __forceinline__ float bf2f(unsigned short u) {
    return __uint_as_float(((unsigned)u) << 16);
}
__device__ __forceinline__ unsigned short f2bf(float f) {
    unsigned u = __float_as_uint(f);
    unsigned r = u + 0x7fffu + ((u >> 16) & 1u);   // round-to-nearest-even
    return (unsigned short)(r >> 16);
}
__device__ __forceinline__ float gelu_exact(float x) {
    return 0.5f * x * (1.0f + erff(x * 0.70710678118654752440f));
}
__device__ __forceinline__ float wsum64(float v) {
#pragma unroll
    for (int off = 32; off > 0; off >>= 1) v += __shfl_xor(v, off, 64);
    return v;
}
template<bool F32>
__device__ __forceinline__ float rd(const void* p, int i) {
    if constexpr (F32) return ((const float*)p)[i];
    else return bf2f(((const unsigned short*)p)[i]);
}

// ---------------- detect: fp32 vs bf16 --------------------------------------
extern "C" __global__ void k_detect(const unsigned* __restrict__ g, int* __restrict__ flag) {
    if (threadIdx.x == 0 && blockIdx.x == 0)
        *flag = (g[0] == 0x3F800000u) ? 1 : 0;
}

// ---------------- Kernel A: 3x3 pixel-block channel sums --------------------
// S[b][by][bx][c] = sum_{dy,dx<3} grid[b][3by+dy][3bx+dx][c]
template<bool F32>
__global__ __launch_bounds__(256)
void k_blocksum_t(const void* __restrict__ hin, float* __restrict__ S,
                  const int* __restrict__ flag) {
    if (*flag != (F32 ? 1 : 0)) return;
    int bby = blockIdx.x;              // b*64 + by
    int b = bby >> 6, by = bby & 63;
    for (int item = threadIdx.x; item < 512; item += 256) {
        int bx = item >> 3;
        int c0 = (item & 7) * 8;
        float acc[8] = {0.f, 0.f, 0.f, 0.f, 0.f, 0.f, 0.f, 0.f};
#pragma unroll
        for (int dy = 0; dy < 3; ++dy) {
#pragma unroll
            for (int dx = 0; dx < 3; ++dx) {
                int y = by * 3 + dy, x = bx * 3 + dx;
                size_t base = (((size_t)b * HH + y) * WW + x) * CC + c0;
                if constexpr (F32) {
                    const float4* p = reinterpret_cast<const float4*>((const float*)hin + base);
                    float4 v0 = p[0], v1 = p[1];
                    acc[0] += v0.x; acc[1] += v0.y; acc[2] += v0.z; acc[3] += v0.w;
                    acc[4] += v1.x; acc[5] += v1.y; acc[6] += v1.z; acc[7] += v1.w;
                } else {
                    uint4 v = *reinterpret_cast<const uint4*>((const unsigned short*)hin + base);
                    acc[0] += __uint_as_float(v.x << 16);
                    acc[1] += __uint_as_float(v.x & 0xffff0000u);
                    acc[2] += __uint_as_float(v.y << 16);
                    acc[3] += __uint_as_float(v.y & 0xffff0000u);
                    acc[4] += __uint_as_float(v.z << 16);
                    acc[5] += __uint_as_float(v.z & 0xffff0000u);
                    acc[6] += __uint_as_float(v.w << 16);
                    acc[7] += __uint_as_float(v.w & 0xffff0000u);
                }
            }
        }
        float4* o = reinterpret_cast<float4*>(S + (((size_t)bby) * 64 + bx) * CC + c0);
        o[0] = make_float4(acc[0], acc[1], acc[2], acc[3]);
        o[1] = make_float4(acc[4], acc[5], acc[6], acc[7]);
    }
}

// ---------------- Kernel B: token projection (reg + shifted) ----------------
// rows: mode(2) x b(32) x wy(32) x wx(32) = 65536; one wave computes 16 rows.
template<bool F32>
__global__ __launch_bounds__(256)
void k_token_t(const float* __restrict__ S,
               const void* __restrict__ Wt, const void* __restrict__ bt,
               const void* __restrict__ gt, const void* __restrict__ bet,
               float* __restrict__ tok, const int* __restrict__ flag) {
    if (*flag != (F32 ? 1 : 0)) return;
    int lane = threadIdx.x & 63;
    int wg = blockIdx.x * 4 + (threadIdx.x >> 6);
    float Wc[64];
#pragma unroll
    for (int k = 0; k < 64; ++k) Wc[k] = rd<F32>(Wt, k * 64 + lane);
    float bias = rd<F32>(bt, lane);
    float gg = rd<F32>(gt, lane);
    float bb = rd<F32>(bet, lane);
    int row0 = wg * 16;
    for (int i = 0; i < 16; ++i) {
        int row = row0 + i;
        int mode = row >> 15;
        int r = row & 32767;
        int b = r >> 10, wy = (r >> 5) & 31, wx = r & 31;
        int r0, r1, c0, c1;
        if (mode == 0) { r0 = 2 * wy;     r1 = 2 * wy + 1;        c0 = 2 * wx;     c1 = 2 * wx + 1; }
        else           { r0 = 2 * wy + 1; r1 = (2 * wy + 2) & 63; c0 = 2 * wx + 1; c1 = (2 * wx + 2) & 63; }
        const float* Sb = S + (size_t)b * 64 * 64 * 64;
        float pooled = (Sb[(r0 * 64 + c0) * 64 + lane] + Sb[(r0 * 64 + c1) * 64 + lane] +
                        Sb[(r1 * 64 + c0) * 64 + lane] + Sb[(r1 * 64 + c1) * 64 + lane]) * (1.0f / 36.0f);
        float y = bias;
#pragma unroll
        for (int k = 0; k < 64; ++k) y += __shfl(pooled, k, 64) * Wc[k];
        float m = wsum64(y) * (1.0f / 64.0f);
        float d = y - m;
        float v = wsum64(d * d) * (1.0f / 64.0f);
        float z = d * rsqrtf(v + 1e-5f) * gg + bb;
        tok[(size_t)row * 64 + lane] = gelu_exact(z);
    }
}

// ---------------- Kernel C: fuse + out blocks on distinct rows --------------
// rows: b(32) x wy(32) x wx(32) x q(4) = 131072. ctx fp32 (into S region).
template<bool F32>
__global__ __launch_bounds__(256)
void k_ctx_t(const float* __restrict__ tok,
             const void* __restrict__ Wf, const void* __restrict__ bf_,
             const void* __restrict__ gf, const void* __restrict__ bef,
             const void* __restrict__ Wo, const void* __restrict__ bo_,
             const void* __restrict__ go, const void* __restrict__ beo,
             float* __restrict__ ctx, const int* __restrict__ flag) {
    if (*flag != (F32 ? 1 : 0)) return;
    int lane = threadIdx.x & 63;
    int wg = blockIdx.x * 4 + (threadIdx.x >> 6);
    float WfC[64], WoC[64];
#pragma unroll
    for (int k = 0; k < 64; ++k) WfC[k] = rd<F32>(Wf, k * 64 + lane);
#pragma unroll
    for (int k = 0; k < 64; ++k) WoC[k] = rd<F32>(Wo, k * 64 + lane);
    float fb = rd<F32>(bf_, lane), fg = rd<F32>(gf, lane), fbe = rd<F32>(bef, lane);
    float ob = rd<F32>(bo_, lane), og = rd<F32>(go, lane), obe = rd<F32>(beo, lane);
    int row0 = wg * 16;
    for (int i = 0; i < 16; ++i) {
        int row = row0 + i;
        int b = row >> 12;
        int rem = row & 4095;
        int wy = rem >> 7, wx = (rem >> 2) & 31, q = rem & 3;
        int sy = (wy + 31 + (q >> 1)) & 31;
        int sx = (wx + 31 + (q & 1)) & 31;
        const float* t0 = tok + (size_t)b * 65536;
        const float* t1 = tok + 2097152 + (size_t)b * 65536;
        float m = t0[(wy * 32 + wx) * 64 + lane] + t1[(sy * 32 + sx) * 64 + lane];
        // fuse block
        float y = fb;
#pragma unroll
        for (int k = 0; k < 64; ++k) y += __shfl(m, k, 64) * WfC[k];
        float mu = wsum64(y) * (1.0f / 64.0f);
        float d = y - mu;
        float var = wsum64(d * d) * (1.0f / 64.0f);
        float h1 = gelu_exact(d * rsqrtf(var + 1e-5f) * fg + fbe);
        // out block
        float z = ob;
#pragma unroll
        for (int k = 0; k < 64; ++k) z += __shfl(h1, k, 64) * WoC[k];
        mu = wsum64(z) * (1.0f / 64.0f);
        d = z - mu;
        var = wsum64(d * d) * (1.0f / 64.0f);
        ctx[(size_t)row * 64 + lane] = gelu_exact(d * rsqrtf(var + 1e-5f) * og + obe);
    }
}

// ---------------- Kernel D: broadcast ctx rows to 3x3 patches ---------------
template<bool F32>
__global__ __launch_bounds__(256)
void k_bcast_t(const float* __restrict__ ctx, void* __restrict__ outv,
               const int* __restrict__ flag) {
    if (*flag != (F32 ? 1 : 0)) return;
    int bid = blockIdx.x;          // b*192 + y
    int b = bid / 192, y = bid - b * 192;
    int wy = y / 6;
    int qy = (y - wy * 6) >= 3;
    const float* base = ctx + (size_t)b * 262144 + (size_t)wy * 8192 + qy * 128;
    size_t outbase = (size_t)bid * (WW * CC);
    for (int item = threadIdx.x; item < 1536; item += 256) {
        int x = item >> 3;
        int c0 = (item & 7) * 8;
        int wx = x / 6;
        int qx = (x - wx * 6) >= 3;
        const float* src = base + wx * 256 + qx * 64 + c0;
        if constexpr (F32) {
            float4* dst = reinterpret_cast<float4*>((float*)outv + outbase + (size_t)x * 64 + c0);
            dst[0] = *reinterpret_cast<const float4*>(src);
            dst[1] = *reinterpret_cast<const float4*>(src + 4);
        } else {
            uint4 v;
            v.x = (unsigned)f2bf(src[0]) | ((unsigned)f2bf(src[1]) << 16);
            v.y = (unsigned)f2bf(src[2]) | ((unsigned)f2bf(src[3]) << 16);
            v.z = (unsigned)f2bf(src[4]) | ((unsigned)f2bf(src[5]) << 16);
            v.w = (unsigned)f2bf(src[6]) | ((unsigned)f2bf(src[7]) << 16);
            *reinterpret_cast<uint4*>((unsigned short*)outv + outbase + (size_t)x * 64 + c0) = v;
        }
    }
}

extern "C" void kernel_launch(void* const* d_in, const int* in_sizes, int n_in,
                              void* d_out, int out_size, void* d_ws, size_t ws_size,
                              hipStream_t stream) {
    const void* h   = d_in[0];
    const void* tW  = d_in[1];
    const void* tb  = d_in[2];
    const void* tg  = d_in[3];
    const void* tbe = d_in[4];
    const void* fW  = d_in[5];
    const void* fb  = d_in[6];
    const void* fg  = d_in[7];
    const void* fbe = d_in[8];
    const void* oW  = d_in[9];
    const void* ob  = d_in[10];
    const void* og  = d_in[11];
    const void* obe = d_in[12];

    char* ws = (char*)d_ws;
    float* S    = (float*)(ws);                    // 33,554,432 B (reused as ctx)
    float* tok  = (float*)(ws + 33554432);         // 16,777,216 B
    float* ctx  = S;                               // ctx fp32 lives in S region
    int* flag   = (int*)(ws + 50331648);

    hipLaunchKernelGGL(k_detect, dim3(1), dim3(64), 0, stream, (const unsigned*)tg, flag);

    hipLaunchKernelGGL((k_blocksum_t<false>), dim3(2048), dim3(256), 0, stream, h, S, flag);
    hipLaunchKernelGGL((k_blocksum_t<true>),  dim3(2048), dim3(256), 0, stream, h, S, flag);

    hipLaunchKernelGGL((k_token_t<false>), dim3(1024), dim3(256), 0, stream,
                       S, tW, tb, tg, tbe, tok, flag);
    hipLaunchKernelGGL((k_token_t<true>),  dim3(1024), dim3(256), 0, stream,
                       S, tW, tb, tg, tbe, tok, flag);

    hipLaunchKernelGGL((k_ctx_t<false>), dim3(2048), dim3(256), 0, stream,
                       tok, fW, fb, fg, fbe, oW, ob, og, obe, ctx, flag);
    hipLaunchKernelGGL((k_ctx_t<true>),  dim3(2048), dim3(256), 0, stream,
                       tok, fW, fb, fg, fbe, oW, ob, og, obe, ctx, flag);

    hipLaunchKernelGGL((k_bcast_t<false>), dim3(6144), dim3(256), 0, stream, ctx, d_out, flag);
    hipLaunchKernelGGL((k_bcast_t<true>),  dim3(6144), dim3(256), 0, stream, ctx, d_out, flag);
}

// Round 3
// 816.896 us; speedup vs baseline: 1.1572x; 1.1572x over previous
//
#include <hip/hip_runtime.h>
#include <math.h>

// GraphSwinWindowContext: B=32, H=W=192, C=64, WS=6, SS=3, NH=NW=32. fp32 in/out
// (confirmed round 2: detect flag fp32 path passed, absmax 1.6e-2).
//
// Output has only B*32*32*4 = 131072 distinct C-vectors (constant per
// (window, quadrant) 3x3 patch) -> per-pixel 64x64 linears collapse 9x.
//
// Round-3 changes vs round 2:
//  * k_ctx held 128 floats of weights -> VGPR cap 112 -> scratch spill
//    (the 296us/20% VALUBusy dispatch). Split into k_fuse + k_outbc, each
//    holding ONE 64-float weight column -> no spill.
//  * k_outbc fuses the out-projection with the 3x3 broadcast store (kills
//    the ctx intermediate entirely).
//  * dtype detect + dead bf16 templates removed.
//
// Pipeline:
//  A) k_blocksum: 3x3-pixel block sums S[B,64,64,C]           (reads 302MB)
//  B) k_token:    pooled(reg/shift) -> lin+LN+GELU -> tok     (65536 rows)
//  C) k_fuse:     tokreg+tokshift -> lin+LN+GELU -> h1        (131072 rows)
//  D) k_outbc:    h1 -> lin+LN+GELU -> broadcast 3x3 to out   (writes 302MB)
//
// ws layout:
//  [0, 33554432)        : S fp32 [B][64][64][C]   -- reused as h1 after k_token
//  [33554432, 50331648) : tok fp32 [2][B][32][32][C]

#define HH 192
#define WW 192
#define CC 64

__device__ __forceinline__ float gelu_exact(float x) {
    return 0.5f * x * (1.0f + erff(x * 0.70710678118654752440f));
}
__device__ __forceinline__ float wsum64(float v) {
#pragma unroll
    for (int off = 32; off > 0; off >>= 1) v += __shfl_xor(v, off, 64);
    return v;
}

// ---------------- Kernel A: 3x3 pixel-block channel sums --------------------
// S[b][by][bx][c] = sum_{dy,dx<3} grid[b][3by+dy][3bx+dx][c], by,bx in [0,64)
extern "C" __global__ __launch_bounds__(256)
void k_blocksum(const float* __restrict__ h, float* __restrict__ S) {
    int bby = blockIdx.x;              // b*64 + by
    int b = bby >> 6, by = bby & 63;
    for (int item = threadIdx.x; item < 512; item += 256) {
        int bx = item >> 3;
        int c0 = (item & 7) * 8;
        float acc[8] = {0.f, 0.f, 0.f, 0.f, 0.f, 0.f, 0.f, 0.f};
#pragma unroll
        for (int dy = 0; dy < 3; ++dy) {
#pragma unroll
            for (int dx = 0; dx < 3; ++dx) {
                int y = by * 3 + dy, x = bx * 3 + dx;
                const float4* p = reinterpret_cast<const float4*>(
                    h + (((size_t)b * HH + y) * WW + x) * CC + c0);
                float4 v0 = p[0], v1 = p[1];
                acc[0] += v0.x; acc[1] += v0.y; acc[2] += v0.z; acc[3] += v0.w;
                acc[4] += v1.x; acc[5] += v1.y; acc[6] += v1.z; acc[7] += v1.w;
            }
        }
        float4* o = reinterpret_cast<float4*>(S + (((size_t)bby) * 64 + bx) * CC + c0);
        o[0] = make_float4(acc[0], acc[1], acc[2], acc[3]);
        o[1] = make_float4(acc[4], acc[5], acc[6], acc[7]);
    }
}

// ---------------- Kernel B: token projection (reg + shifted) ----------------
// rows: mode(2) x b(32) x wy(32) x wx(32) = 65536; one wave computes 16 rows.
extern "C" __global__ __launch_bounds__(256)
void k_token(const float* __restrict__ S,
             const float* __restrict__ Wt, const float* __restrict__ bt,
             const float* __restrict__ gt, const float* __restrict__ bet,
             float* __restrict__ tok) {
    int lane = threadIdx.x & 63;
    int wg = blockIdx.x * 4 + (threadIdx.x >> 6);
    float Wc[64];
#pragma unroll
    for (int k = 0; k < 64; ++k) Wc[k] = Wt[k * 64 + lane];
    float bias = bt[lane], gg = gt[lane], bb = bet[lane];
    int row0 = wg * 16;
    for (int i = 0; i < 16; ++i) {
        int row = row0 + i;
        int mode = row >> 15;
        int r = row & 32767;
        int b = r >> 10, wy = (r >> 5) & 31, wx = r & 31;
        int r0, r1, c0, c1;
        if (mode == 0) { r0 = 2 * wy;     r1 = 2 * wy + 1;        c0 = 2 * wx;     c1 = 2 * wx + 1; }
        else           { r0 = 2 * wy + 1; r1 = (2 * wy + 2) & 63; c0 = 2 * wx + 1; c1 = (2 * wx + 2) & 63; }
        const float* Sb = S + (size_t)b * 64 * 64 * 64;
        float pooled = (Sb[(r0 * 64 + c0) * 64 + lane] + Sb[(r0 * 64 + c1) * 64 + lane] +
                        Sb[(r1 * 64 + c0) * 64 + lane] + Sb[(r1 * 64 + c1) * 64 + lane]) * (1.0f / 36.0f);
        float y = bias;
#pragma unroll
        for (int k = 0; k < 64; ++k) y += __shfl(pooled, k, 64) * Wc[k];
        float m = wsum64(y) * (1.0f / 64.0f);
        float d = y - m;
        float v = wsum64(d * d) * (1.0f / 64.0f);
        float z = d * rsqrtf(v + 1e-5f) * gg + bb;
        tok[(size_t)row * 64 + lane] = gelu_exact(z);
    }
}

// ---------------- Kernel C: fuse block ---------------------------------------
// rows: b(32) x wy(32) x wx(32) x q(4) = 131072; one wave computes 16 rows.
extern "C" __global__ __launch_bounds__(256)
void k_fuse(const float* __restrict__ tok,
            const float* __restrict__ Wf, const float* __restrict__ bf_,
            const float* __restrict__ gf, const float* __restrict__ bef,
            float* __restrict__ h1) {
    int lane = threadIdx.x & 63;
    int wg = blockIdx.x * 4 + (threadIdx.x >> 6);
    float Wc[64];
#pragma unroll
    for (int k = 0; k < 64; ++k) Wc[k] = Wf[k * 64 + lane];
    float fb = bf_[lane], fg = gf[lane], fbe = bef[lane];
    int row0 = wg * 16;
    for (int i = 0; i < 16; ++i) {
        int row = row0 + i;
        int b = row >> 12;
        int rem = row & 4095;
        int wy = rem >> 7, wx = (rem >> 2) & 31, q = rem & 3;
        int sy = (wy + 31 + (q >> 1)) & 31;
        int sx = (wx + 31 + (q & 1)) & 31;
        const float* t0 = tok + (size_t)b * 65536;
        const float* t1 = tok + 2097152 + (size_t)b * 65536;
        float m = t0[(wy * 32 + wx) * 64 + lane] + t1[(sy * 32 + sx) * 64 + lane];
        float y = fb;
#pragma unroll
        for (int k = 0; k < 64; ++k) y += __shfl(m, k, 64) * Wc[k];
        float mu = wsum64(y) * (1.0f / 64.0f);
        float d = y - mu;
        float var = wsum64(d * d) * (1.0f / 64.0f);
        h1[(size_t)row * 64 + lane] = gelu_exact(d * rsqrtf(var + 1e-5f) * fg + fbe);
    }
}

// ---------------- Kernel D: out block + 3x3 broadcast store ------------------
extern "C" __global__ __launch_bounds__(256)
void k_outbc(const float* __restrict__ h1,
             const float* __restrict__ Wo, const float* __restrict__ bo_,
             const float* __restrict__ go, const float* __restrict__ beo,
             float* __restrict__ out) {
    int lane = threadIdx.x & 63;
    int wg = blockIdx.x * 4 + (threadIdx.x >> 6);
    float Wc[64];
#pragma unroll
    for (int k = 0; k < 64; ++k) Wc[k] = Wo[k * 64 + lane];
    float ob = bo_[lane], og = go[lane], obe = beo[lane];
    int row0 = wg * 16;
    for (int i = 0; i < 16; ++i) {
        int row = row0 + i;
        float m = h1[(size_t)row * 64 + lane];
        float z = ob;
#pragma unroll
        for (int k = 0; k < 64; ++k) z += __shfl(m, k, 64) * Wc[k];
        float mu = wsum64(z) * (1.0f / 64.0f);
        float d = z - mu;
        float var = wsum64(d * d) * (1.0f / 64.0f);
        float o = gelu_exact(d * rsqrtf(var + 1e-5f) * og + obe);
        // broadcast to the 3x3 pixel patch
        int b = row >> 12;
        int rem = row & 4095;
        int wy = rem >> 7, wx = (rem >> 2) & 31, q = rem & 3;
        int y0 = wy * 6 + (q >> 1) * 3;
        int x0 = wx * 6 + (q & 1) * 3;
        float* obase = out + (((size_t)b * HH + y0) * WW + x0) * CC + lane;
#pragma unroll
        for (int dy = 0; dy < 3; ++dy) {
#pragma unroll
            for (int dx = 0; dx < 3; ++dx) {
                obase[((size_t)dy * WW + dx) * CC] = o;
            }
        }
    }
}

extern "C" void kernel_launch(void* const* d_in, const int* in_sizes, int n_in,
                              void* d_out, int out_size, void* d_ws, size_t ws_size,
                              hipStream_t stream) {
    const float* h   = (const float*)d_in[0];
    const float* tW  = (const float*)d_in[1];
    const float* tb  = (const float*)d_in[2];
    const float* tg  = (const float*)d_in[3];
    const float* tbe = (const float*)d_in[4];
    const float* fW  = (const float*)d_in[5];
    const float* fb  = (const float*)d_in[6];
    const float* fg  = (const float*)d_in[7];
    const float* fbe = (const float*)d_in[8];
    const float* oW  = (const float*)d_in[9];
    const float* ob  = (const float*)d_in[10];
    const float* og  = (const float*)d_in[11];
    const float* obe = (const float*)d_in[12];
    float* out = (float*)d_out;

    char* ws = (char*)d_ws;
    float* S   = (float*)(ws);              // 33,554,432 B; reused as h1
    float* tok = (float*)(ws + 33554432);   // 16,777,216 B
    float* h1  = S;

    hipLaunchKernelGGL(k_blocksum, dim3(2048), dim3(256), 0, stream, h, S);
    hipLaunchKernelGGL(k_token, dim3(1024), dim3(256), 0, stream,
                       S, tW, tb, tg, tbe, tok);
    hipLaunchKernelGGL(k_fuse, dim3(2048), dim3(256), 0, stream,
                       tok, fW, fb, fg, fbe, h1);
    hipLaunchKernelGGL(k_outbc, dim3(2048), dim3(256), 0, stream,
                       h1, oW, ob, og, obe, out);
}